// Round 5
// baseline (336.766 us; speedup 1.0000x reference)
//
#include <hip/hip_runtime.h>

#define NPOINTS 262144
#define SUMH 224
#define SUMW 221
#define NREG 500

// ---------- DPP helpers ----------
__device__ __forceinline__ float rlane(float v, int l) {
  return __int_as_float(__builtin_amdgcn_readlane(__float_as_int(v), l));
}
template<int CTRL>
__device__ __forceinline__ float dpp0(float x) {   // 0-fill on invalid
  return __int_as_float(__builtin_amdgcn_update_dpp(0, __float_as_int(x), CTRL, 0xF, 0xF, true));
}
template<int CTRL, int RM>
__device__ __forceinline__ float dpp_rm(float x) { // row-masked, old=0
  return __int_as_float(__builtin_amdgcn_update_dpp(0, __float_as_int(x), CTRL, RM, 0xF, false));
}
template<int CTRL>
__device__ __forceinline__ float dpp_max_(float x) {
  return fmaxf(x, __int_as_float(__builtin_amdgcn_update_dpp(__float_as_int(x), __float_as_int(x), CTRL, 0xF, 0xF, false)));
}
// 64-lane reduce / scan (region kernel)
__device__ __forceinline__ float wave_sum(float x) {
  x += dpp0<0x111>(x); x += dpp0<0x112>(x); x += dpp0<0x114>(x); x += dpp0<0x118>(x);
  x += dpp_rm<0x142, 0xA>(x); x += dpp_rm<0x143, 0xC>(x);
  return rlane(x, 63);
}
__device__ __forceinline__ float wave_max(float x) {
  x = dpp_max_<0x111>(x); x = dpp_max_<0x112>(x); x = dpp_max_<0x114>(x);
  x = dpp_max_<0x118>(x); x = dpp_max_<0x142>(x); x = dpp_max_<0x143>(x);
  return rlane(x, 63);
}
__device__ __forceinline__ float wave_scan_incl(float x) {
  x += dpp0<0x111>(x); x += dpp0<0x112>(x); x += dpp0<0x114>(x); x += dpp0<0x118>(x);
  x += dpp_rm<0x142, 0xA>(x);   // row_bcast:15 -> rows 1,3
  x += dpp_rm<0x143, 0xC>(x);   // row_bcast:31 -> rows 2,3
  return x;
}
// 32-lane group-local inclusive scan: pure DPP, no LDS op.
// (= wave_scan_incl minus the cross-32 row_bcast31 stage.)
__device__ __forceinline__ float grp32_scan_incl(float x) {
  x += dpp0<0x111>(x); x += dpp0<0x112>(x); x += dpp0<0x114>(x); x += dpp0<0x118>(x);
  x += dpp_rm<0x142, 0xA>(x);   // row0.l15 -> row1, row2.l15 -> row3 (group-local)
  return x;
}
__device__ __forceinline__ float bperm(int byteidx, float v) {
  return __int_as_float(__builtin_amdgcn_ds_bpermute(byteidx, __float_as_int(v)));
}

// ---------- Kernel 1: per-ROI bin-edge table (BL) + gathered hemb rows (U) ----------
template<int M, int SRC, int DST, int NB>
__device__ __forceinline__ void region_level(const float* __restrict__ wrow,
    float* __restrict__ BL, int lane)
{
  float v0 = (lane < M) ? wrow[SRC + lane] : -1e30f;
  float v1 = -1e30f;
  if constexpr (NB == 128) { if (lane + 64 < M) v1 = wrow[SRC + lane + 64]; }
  float m = wave_max(fmaxf(v0, v1));
  float e0 = __expf(v0 - m);                 // 0 for padded slots
  float e1 = (NB == 128) ? __expf(v1 - m) : 0.0f;
  float sm = wave_sum(e0 + e1);
  float inv = 1.0f / sm;
  float incl0 = wave_scan_incl(e0);
  if (lane == 0) BL[DST] = 0.0f;
  if (lane < M) BL[DST + 1 + lane] = (lane == M - 1) ? 1.0f : incl0 * inv;
  if constexpr (NB == 128) {
    float incl1 = wave_scan_incl(e1) + rlane(incl0, 63);
    int k = 64 + lane;
    if (k < M) BL[DST + 1 + k] = (k == M - 1) ? 1.0f : incl1 * inv;
  }
}

__global__ void __launch_bounds__(64) region_kernel(
    const int* __restrict__ roi, const float* __restrict__ wemb,
    const float* __restrict__ hemb, float* __restrict__ wsBL,
    float* __restrict__ wsU)
{
  int rix = blockIdx.x;
  int lane = threadIdx.x;
  int greg = roi[rix];
  const float* wrow = wemb + (size_t)greg * SUMW;
  float* BL = wsBL + (size_t)rix * SUMH;
  region_level<127,   0,   0, 128>(wrow, BL, lane);
  region_level< 63, 127, 128,  64>(wrow, BL, lane);
  region_level< 31, 190, 192,  32>(wrow, BL, lane);
  // gather this ROI's hemb row so the point kernel indexes by rix directly
  const float* hrow = hemb + (size_t)greg * SUMH;
  float* U = wsU + (size_t)rix * SUMH;
  U[lane]       = hrow[lane];
  U[lane + 64]  = hrow[lane + 64];
  U[lane + 128] = hrow[lane + 128];
  if (lane < 32) U[lane + 192] = hrow[lane + 192];
}

// ---------- Kernel 2: 32-lane groups, 2-deep point pipeline (4 pts/wave) ----------

struct PtState {
  float4 a0, b0, e0;   // level0 (C=4): u, d, bl
  float2 a1, b1, e1;   // level1 (C=2)
  float  a2, b2, e2;   // level2 (C=1)
  float  xv;
  int    pid;
};

__device__ __forceinline__ void load_pt(PtState& P, int pid, int s,
    const float* __restrict__ x, const int* __restrict__ lix,
    const float* __restrict__ delta,
    const float* __restrict__ wsU, const float* __restrict__ wsBL)
{
  P.pid = pid;
  P.xv = x[pid];
  int r = lix[pid];
  const float* U  = wsU  + (size_t)r * SUMH;
  const float* D  = delta + (size_t)pid * SUMH;
  const float* BL = wsBL + (size_t)r * SUMH;
  int c0 = s * 4;
  P.a0 = *(const float4*)(U + c0);  P.b0 = *(const float4*)(D + c0);
  P.e0 = *(const float4*)(BL + c0);
  int c1 = 128 + s * 2;
  P.a1 = *(const float2*)(U + c1);  P.b1 = *(const float2*)(D + c1);
  P.e1 = *(const float2*)(BL + c1);
  int c2 = 192 + s;
  P.a2 = U[c2]; P.b2 = D[c2]; P.e2 = BL[c2];
}

// Hoisted (xv-independent) per-level material: heights, neighbor pulls,
// per-bin widths, GLOBAL trapezoid prefix pre[i] (cross-lane exclusive scan
// + local prefix), and 1/area. The scan is pure-DPP group-local; area is the
// inclusive scan at the group's lane 31.
template<int C>
__device__ __forceinline__ void prep_level(int s, int nb_idx, int a31,
    const float (&u)[C], const float (&d)[C], const float (&blin)[C],
    float (&he)[C], float (&bl)[C], float (&w)[C], float (&pre)[C],
    float& heN, float& blN, float& inva)
{
#pragma unroll
  for (int i = 0; i < C; ++i) { he[i] = __expf(u[i] + d[i]); bl[i] = blin[i]; }
  heN = bperm(nb_idx, he[0]);
  blN = bperm(nb_idx, bl[0]);
  if (s == 31) blN = bl[C - 1];          // phantom last bin: w = 0, kills garbage
  float ltot = 0.0f;
#pragma unroll
  for (int i = 0; i < C; ++i) {
    float bn = (i < C - 1) ? bl[i + 1] : blN;
    float hn = (i < C - 1) ? he[i + 1] : heN;
    w[i] = bn - bl[i];
    pre[i] = ltot;                       // local prefix before bin i
    ltot += 0.5f * (he[i] + hn) * w[i];
  }
  float incl = grp32_scan_incl(ltot);
  float cross = incl - ltot;             // exclusive cross-lane prefix
  float area = bperm(a31, incl);         // group total (lane 31 of group)
  inva = __builtin_amdgcn_rcpf(area);
#pragma unroll
  for (int i = 0; i < C; ++i) pre[i] += cross;  // global trapezoid cdf at bin left
}

// xv-dependent pass: compares -> one-hot cndmask selects -> ballot/ctz ->
// 5 batched bpermutes (single lgkm wait) -> epilogue. No reduction on the
// critical path.
template<int C>
__device__ __forceinline__ void apply_level(float& xv, float& ldr, int s, int gbase,
    const float (&he)[C], float heN, const float (&bl)[C], float blN,
    const float (&w)[C], const float (&pre)[C], float inva)
{
  bool f[C + 1];
  f[0] = (s == 0) ? true : (bl[0] < xv);
#pragma unroll
  for (int i = 1; i < C; ++i) f[i] = (bl[i] < xv);
  if (s == 31) f[C - 1] = false;         // last global edge never counted
  f[C] = (blN < xv);                     // next lane's first flag
  float hl = 0.0f, hr = 0.0f, loc = 0.0f, inw = 0.0f, pt = 0.0f;
  bool own = false;
#pragma unroll
  for (int i = 0; i < C; ++i) {
    bool oi = f[i] && !f[i + 1];         // unique owner of containing bin
    own = own || oi;
    float hn = (i < C - 1) ? he[i + 1] : heN;
    hl  = oi ? he[i]  : hl;
    hr  = oi ? hn     : hr;
    loc = oi ? bl[i]  : loc;
    inw = oi ? w[i]   : inw;
    pt  = oi ? pre[i] : pt;
  }
  unsigned long long m64 = __ballot(own);
  unsigned gm = gbase ? (unsigned)(m64 >> 32) : (unsigned)m64;
  int ob = ((__builtin_ctz(gm) + gbase) << 2);
  hl  = bperm(ob, hl);
  hr  = bperm(ob, hr);
  loc = bperm(ob, loc);
  inw = bperm(ob, inw);
  pt  = bperm(ob, pt);
  float alpha = (xv - loc) * __builtin_amdgcn_rcpf(inw);
  float dh = hr - hl;
  xv = ((0.5f * dh * alpha + hl) * alpha * inw + pt) * inva;
  ldr *= (alpha * dh + hl) * inva;       // d(out)/dx factor; log taken once at end
}

__device__ __forceinline__ void compute_pt(const PtState& P, int s, int gbase,
                                           int nb_idx, int a31,
                                           float* __restrict__ out)
{
  float u0[4] = {P.a0.x, P.a0.y, P.a0.z, P.a0.w};
  float d0[4] = {P.b0.x, P.b0.y, P.b0.z, P.b0.w};
  float c0[4] = {P.e0.x, P.e0.y, P.e0.z, P.e0.w};
  float u1[2] = {P.a1.x, P.a1.y};
  float d1[2] = {P.b1.x, P.b1.y};
  float c1[2] = {P.e1.x, P.e1.y};
  float u2[1] = {P.a2};
  float d2[1] = {P.b2};
  float c2[1] = {P.e2};

  float he0[4], bl0[4], w0[4], pre0[4], heN0, blN0, inva0;
  float he1[2], bl1[2], w1[2], pre1[2], heN1, blN1, inva1;
  float he2[1], bl2[1], w2[1], pre2[1], heN2, blN2, inva2;
  prep_level<4>(s, nb_idx, a31, u0, d0, c0, he0, bl0, w0, pre0, heN0, blN0, inva0);
  prep_level<2>(s, nb_idx, a31, u1, d1, c1, he1, bl1, w1, pre1, heN1, blN1, inva1);
  prep_level<1>(s, nb_idx, a31, u2, d2, c2, he2, bl2, w2, pre2, heN2, blN2, inva2);

  float xv = P.xv;
  float ldr = 1.0f;
  apply_level<4>(xv, ldr, s, gbase, he0, heN0, bl0, blN0, w0, pre0, inva0);
  apply_level<2>(xv, ldr, s, gbase, he1, heN1, bl1, blN1, w1, pre1, inva1);
  apply_level<1>(xv, ldr, s, gbase, he2, heN2, bl2, blN2, w2, pre2, inva2);
  if (s == 0) {
    out[P.pid] = xv;
    out[NPOINTS + P.pid] = __log2f(ldr) * 0.69314718055994531f;
  }
}

__global__ void __launch_bounds__(256, 4) spline_kernel(
    const float* __restrict__ x,
    const int* __restrict__ lix, const float* __restrict__ delta,
    const float* __restrict__ wsU, const float* __restrict__ wsBL,
    float* __restrict__ out)
{
  int tid  = (int)(blockIdx.x * blockDim.x + threadIdx.x);
  int wid  = tid >> 6;
  int lane = (int)(threadIdx.x & 63);
  int grp  = lane >> 5;            // 2 groups per wave
  int s    = lane & 31;            // 32-lane group, lanes <-> columns
  int gbase = lane & 32;           // group base lane within wave
  int base = wid * 4;              // 4 points per wave (2 pipelined pairs)
  int nb_idx = ((lane + 1) & 63) << 2;
  int a31 = (gbase + 31) << 2;     // group's lane 31 (byte index for bperm)

  // issue BOTH pairs' load chains before any compute (2-deep pipeline)
  PtState A, B;
  load_pt(A, base + grp,     s, x, lix, delta, wsU, wsBL);
  load_pt(B, base + 2 + grp, s, x, lix, delta, wsU, wsBL);

  compute_pt(A, s, gbase, nb_idx, a31, out);
  compute_pt(B, s, gbase, nb_idx, a31, out);
}

// ---------- launch ----------

extern "C" void kernel_launch(void* const* d_in, const int* in_sizes, int n_in,
                              void* d_out, int out_size, void* d_ws, size_t ws_size,
                              hipStream_t stream) {
  const float* x     = (const float*)d_in[0];
  const int*   roi   = (const int*)  d_in[1];
  const int*   lix   = (const int*)  d_in[2];
  const float* delta = (const float*)d_in[3];
  const float* hemb  = (const float*)d_in[4];
  const float* wemb  = (const float*)d_in[5];

  float* wsBL = (float*)d_ws;                    // [500][224]
  float* wsU  = wsBL + (size_t)NREG * SUMH;      // [500][224]

  region_kernel<<<NREG, 64, 0, stream>>>(roi, wemb, hemb, wsBL, wsU);
  spline_kernel<<<NPOINTS / 16, 256, 0, stream>>>(x, lix, delta,
                                                  wsU, wsBL, (float*)d_out);
}

// Round 7
// 334.882 us; speedup vs baseline: 1.0056x; 1.0056x over previous
//
#include <hip/hip_runtime.h>

#define NPOINTS 262144
#define SUMH 224
#define SUMW 221
#define NREG 500

typedef float nfloat4 __attribute__((ext_vector_type(4)));
typedef float nfloat2 __attribute__((ext_vector_type(2)));

// ---------- DPP helpers ----------
__device__ __forceinline__ float rlane(float v, int l) {
  return __int_as_float(__builtin_amdgcn_readlane(__float_as_int(v), l));
}
template<int CTRL>
__device__ __forceinline__ float dpp0(float x) {   // 0-fill on invalid
  return __int_as_float(__builtin_amdgcn_update_dpp(0, __float_as_int(x), CTRL, 0xF, 0xF, true));
}
template<int CTRL, int RM>
__device__ __forceinline__ float dpp_rm(float x) { // row-masked, old=0
  return __int_as_float(__builtin_amdgcn_update_dpp(0, __float_as_int(x), CTRL, RM, 0xF, false));
}
template<int CTRL>
__device__ __forceinline__ float dpp_max_(float x) {
  return fmaxf(x, __int_as_float(__builtin_amdgcn_update_dpp(__float_as_int(x), __float_as_int(x), CTRL, 0xF, 0xF, false)));
}
// 64-lane reduce / scan (region kernel)
__device__ __forceinline__ float wave_sum(float x) {
  x += dpp0<0x111>(x); x += dpp0<0x112>(x); x += dpp0<0x114>(x); x += dpp0<0x118>(x);
  x += dpp_rm<0x142, 0xA>(x); x += dpp_rm<0x143, 0xC>(x);
  return rlane(x, 63);
}
__device__ __forceinline__ float wave_max(float x) {
  x = dpp_max_<0x111>(x); x = dpp_max_<0x112>(x); x = dpp_max_<0x114>(x);
  x = dpp_max_<0x118>(x); x = dpp_max_<0x142>(x); x = dpp_max_<0x143>(x);
  return rlane(x, 63);
}
__device__ __forceinline__ float wave_scan_incl(float x) {
  x += dpp0<0x111>(x); x += dpp0<0x112>(x); x += dpp0<0x114>(x); x += dpp0<0x118>(x);
  x += dpp_rm<0x142, 0xA>(x);   // row_bcast:15 -> rows 1,3
  x += dpp_rm<0x143, 0xC>(x);   // row_bcast:31 -> rows 2,3
  return x;
}
// 32-lane group sum: 16-lane DPP butterfly + xor16 via ds_swizzle
__device__ __forceinline__ float grp32_sum(float x) {
  x += dpp0<0xB1>(x);    // xor1
  x += dpp0<0x4E>(x);    // xor2
  x += dpp0<0x141>(x);   // row_half_mirror
  x += dpp0<0x140>(x);   // row_mirror
  x += __int_as_float(__builtin_amdgcn_ds_swizzle(__float_as_int(x), 0x401F)); // xor16
  return x;
}
__device__ __forceinline__ float bperm(int byteidx, float v) {
  return __int_as_float(__builtin_amdgcn_ds_bpermute(byteidx, __float_as_int(v)));
}

// ---------- Kernel 1: per-ROI bin-edge table (BL) + gathered hemb rows (U) ----------
template<int M, int SRC, int DST, int NB>
__device__ __forceinline__ void region_level(const float* __restrict__ wrow,
    float* __restrict__ BL, int lane)
{
  float v0 = (lane < M) ? wrow[SRC + lane] : -1e30f;
  float v1 = -1e30f;
  if constexpr (NB == 128) { if (lane + 64 < M) v1 = wrow[SRC + lane + 64]; }
  float m = wave_max(fmaxf(v0, v1));
  float e0 = __expf(v0 - m);                 // 0 for padded slots
  float e1 = (NB == 128) ? __expf(v1 - m) : 0.0f;
  float sm = wave_sum(e0 + e1);
  float inv = 1.0f / sm;
  float incl0 = wave_scan_incl(e0);
  if (lane == 0) BL[DST] = 0.0f;
  if (lane < M) BL[DST + 1 + lane] = (lane == M - 1) ? 1.0f : incl0 * inv;
  if constexpr (NB == 128) {
    float incl1 = wave_scan_incl(e1) + rlane(incl0, 63);
    int k = 64 + lane;
    if (k < M) BL[DST + 1 + k] = (k == M - 1) ? 1.0f : incl1 * inv;
  }
}

__global__ void __launch_bounds__(64) region_kernel(
    const int* __restrict__ roi, const float* __restrict__ wemb,
    const float* __restrict__ hemb, float* __restrict__ wsBL,
    float* __restrict__ wsU)
{
  int rix = blockIdx.x;
  int lane = threadIdx.x;
  int greg = roi[rix];
  const float* wrow = wemb + (size_t)greg * SUMW;
  float* BL = wsBL + (size_t)rix * SUMH;
  region_level<127,   0,   0, 128>(wrow, BL, lane);
  region_level< 63, 127, 128,  64>(wrow, BL, lane);
  region_level< 31, 190, 192,  32>(wrow, BL, lane);
  // gather this ROI's hemb row so the point kernel indexes by rix directly
  // (removes the lix -> roi -> hemb dependent hop from every point load).
  const float* hrow = hemb + (size_t)greg * SUMH;
  float* U = wsU + (size_t)rix * SUMH;
  U[lane]       = hrow[lane];
  U[lane + 64]  = hrow[lane + 64];
  U[lane + 128] = hrow[lane + 128];
  if (lane < 32) U[lane + 192] = hrow[lane + 192];
}

// ---------- Kernel 2: 32-lane groups, 2-deep point pipeline (4 pts/wave) ----------

struct PtState {
  float4 a0, e0;       // level0 (C=4): u, bl
  nfloat4 b0;          //               d (nontemporal)
  float2 a1, e1;       // level1 (C=2)
  nfloat2 b1;
  float  a2, b2, e2;   // level2 (C=1)
  float  xv;
  int    pid;
};

__device__ __forceinline__ void load_pt(PtState& P, int pid, int s,
    const float* __restrict__ x, const int* __restrict__ lix,
    const float* __restrict__ delta,
    const float* __restrict__ wsU, const float* __restrict__ wsBL)
{
  P.pid = pid;
  P.xv = x[pid];
  int r = lix[pid];
  const float* U  = wsU  + (size_t)r * SUMH;
  const float* D  = delta + (size_t)pid * SUMH;
  const float* BL = wsBL + (size_t)r * SUMH;
  int c0 = s * 4;
  P.a0 = *(const float4*)(U + c0);
  P.b0 = __builtin_nontemporal_load((const nfloat4*)(D + c0));  // delta: streamed once,
  P.e0 = *(const float4*)(BL + c0);                             // don't pollute L2
  int c1 = 128 + s * 2;
  P.a1 = *(const float2*)(U + c1);
  P.b1 = __builtin_nontemporal_load((const nfloat2*)(D + c1));
  P.e1 = *(const float2*)(BL + c1);
  int c2 = 192 + s;
  P.a2 = U[c2];
  P.b2 = __builtin_nontemporal_load(D + c2);
  P.e2 = BL[c2];
}

// One level's xv-dependent pass. All xv-independent material (he, heN, blN,
// inva) is precomputed by the caller. Flags are monotone {1..1,0..0} over the
// flattened (lane-major) edge order; the unique owner slot (f[i] && !f[i+1])
// carries {hl,hr,loc,w} via cndmask one-hot; its lane id comes from
// __ballot + ctz and values are pulled with ds_bpermute.
template<int C>
__device__ __forceinline__ void apply_level(float& xv, float& ldr, int s, int gbase,
    const float (&he)[C], float heN, const float (&bl)[C], float blN, float inva)
{
  bool f[C + 1];
  f[0] = (s == 0) ? true : (bl[0] < xv);
#pragma unroll
  for (int i = 1; i < C; ++i) f[i] = (bl[i] < xv);
  if (s == 31) f[C - 1] = false;          // last global edge never counted
  f[C] = (blN < xv);                      // next lane's first flag (phantom bin w=0)
  float pt = 0.0f, hl = 0.0f, hr = 0.0f, loc = 0.0f, inw = 0.0f;
  bool own = false;
#pragma unroll
  for (int i = 0; i < C; ++i) {
    float bn = (i < C - 1) ? bl[i + 1] : blN;
    float hn = (i < C - 1) ? he[i + 1] : heN;
    float w  = bn - bl[i];
    float tb = 0.5f * (he[i] + hn) * w;
    if (f[i + 1]) pt += tb;               // trapezoid cdf left of owner bin
    bool oi = f[i] && !f[i + 1];          // unique owner of containing bin
    own = own || oi;
    hl  = oi ? he[i] : hl;
    hr  = oi ? hn    : hr;
    loc = oi ? bl[i] : loc;
    inw = oi ? w     : inw;
  }
  pt = grp32_sum(pt);
  unsigned long long m64 = __ballot(own);
  unsigned gm = gbase ? (unsigned)(m64 >> 32) : (unsigned)m64;
  int ob = ((__builtin_ctz(gm) + gbase) << 2);
  hl  = bperm(ob, hl);
  hr  = bperm(ob, hr);
  loc = bperm(ob, loc);
  inw = bperm(ob, inw);
  float alpha = (xv - loc) * __builtin_amdgcn_rcpf(inw);
  float dh = hr - hl;
  xv = ((0.5f * dh * alpha + hl) * alpha * inw + pt) * inva;
  ldr *= (alpha * dh + hl) * inva;        // d(out)/dx factor; log taken once at end
}

__device__ __forceinline__ void compute_pt(const PtState& P, int s, int gbase, int nb_idx,
                                           float* __restrict__ out)
{
  // ---- xv-independent precompute: heights, neighbor pulls, areas ----
  float he0[4] = {__expf(P.a0.x + P.b0.x), __expf(P.a0.y + P.b0.y),
                  __expf(P.a0.z + P.b0.z), __expf(P.a0.w + P.b0.w)};
  float he1[2] = {__expf(P.a1.x + P.b1.x), __expf(P.a1.y + P.b1.y)};
  float he2[1] = {__expf(P.a2 + P.b2)};
  float bl0[4] = {P.e0.x, P.e0.y, P.e0.z, P.e0.w};
  float bl1[2] = {P.e1.x, P.e1.y};
  float bl2[1] = {P.e2};
  float heN0 = bperm(nb_idx, he0[0]);
  float heN1 = bperm(nb_idx, he1[0]);
  float heN2 = bperm(nb_idx, he2[0]);
  float blN0 = bperm(nb_idx, bl0[0]);
  float blN1 = bperm(nb_idx, bl1[0]);
  float blN2 = bperm(nb_idx, bl2[0]);
  if (s == 31) {                // phantom last bin: force w = 0, kill garbage
    blN0 = bl0[3]; blN1 = bl1[1]; blN2 = bl2[0];
  }
  float a0 = 0.0f, a1 = 0.0f, a2;
#pragma unroll
  for (int i = 0; i < 4; ++i) {
    float bn = (i < 3) ? bl0[i + 1] : blN0;
    float hn = (i < 3) ? he0[i + 1] : heN0;
    a0 += 0.5f * (he0[i] + hn) * (bn - bl0[i]);
  }
#pragma unroll
  for (int i = 0; i < 2; ++i) {
    float bn = (i < 1) ? bl1[i + 1] : blN1;
    float hn = (i < 1) ? he1[i + 1] : heN1;
    a1 += 0.5f * (he1[i] + hn) * (bn - bl1[i]);
  }
  a2 = 0.5f * (he2[0] + heN2) * (blN2 - bl2[0]);
  a0 = grp32_sum(a0);
  a1 = grp32_sum(a1);
  a2 = grp32_sum(a2);
  float inva0 = __builtin_amdgcn_rcpf(a0);
  float inva1 = __builtin_amdgcn_rcpf(a1);
  float inva2 = __builtin_amdgcn_rcpf(a2);

  // ---- serial per-level chain (short: flags -> pt reduce -> owner pull) ----
  float xv = P.xv;
  float ldr = 1.0f;
  apply_level<4>(xv, ldr, s, gbase, he0, heN0, bl0, blN0, inva0);
  apply_level<2>(xv, ldr, s, gbase, he1, heN1, bl1, blN1, inva1);
  apply_level<1>(xv, ldr, s, gbase, he2, heN2, bl2, blN2, inva2);
  if (s == 0) {
    out[P.pid] = xv;
    out[NPOINTS + P.pid] = __log2f(ldr) * 0.69314718055994531f;
  }
}

__global__ void __launch_bounds__(256, 4) spline_kernel(
    const float* __restrict__ x,
    const int* __restrict__ lix, const float* __restrict__ delta,
    const float* __restrict__ wsU, const float* __restrict__ wsBL,
    float* __restrict__ out)
{
  int tid  = (int)(blockIdx.x * blockDim.x + threadIdx.x);
  int wid  = tid >> 6;
  int lane = (int)(threadIdx.x & 63);
  int grp  = lane >> 5;            // 2 groups per wave
  int s    = lane & 31;            // 32-lane group, lanes <-> columns
  int gbase = lane & 32;           // group base lane within wave
  int base = wid * 4;              // 4 points per wave (2 pipelined pairs)
  int nb_idx = ((lane + 1) & 63) << 2;

  // issue BOTH pairs' load chains before any compute (2-deep pipeline)
  PtState A, B;
  load_pt(A, base + grp,     s, x, lix, delta, wsU, wsBL);
  load_pt(B, base + 2 + grp, s, x, lix, delta, wsU, wsBL);

  compute_pt(A, s, gbase, nb_idx, out);
  compute_pt(B, s, gbase, nb_idx, out);
}

// ---------- launch ----------

extern "C" void kernel_launch(void* const* d_in, const int* in_sizes, int n_in,
                              void* d_out, int out_size, void* d_ws, size_t ws_size,
                              hipStream_t stream) {
  const float* x     = (const float*)d_in[0];
  const int*   roi   = (const int*)  d_in[1];
  const int*   lix   = (const int*)  d_in[2];
  const float* delta = (const float*)d_in[3];
  const float* hemb  = (const float*)d_in[4];
  const float* wemb  = (const float*)d_in[5];

  float* wsBL = (float*)d_ws;                    // [500][224]
  float* wsU  = wsBL + (size_t)NREG * SUMH;      // [500][224]

  region_kernel<<<NREG, 64, 0, stream>>>(roi, wemb, hemb, wsBL, wsU);
  spline_kernel<<<NPOINTS / 16, 256, 0, stream>>>(x, lix, delta,
                                                  wsU, wsBL, (float*)d_out);
}